// Round 1
// baseline (735.789 us; speedup 1.0000x reference)
//
#include <hip/hip_runtime.h>
#include <stdint.h>

#define CAP 128   // max nnz per normalized-adj row (Poisson(41): P(>=128) ~ 1e-26)

typedef __attribute__((ext_vector_type(8))) short bf16x8;
typedef __attribute__((ext_vector_type(4))) float f32x4;

typedef __attribute__((address_space(3))) uint32_t lds_u32;
typedef __attribute__((address_space(1))) const uint32_t glb_u32;

__device__ __forceinline__ unsigned short f2bf(float f) {
  union { float f; uint32_t u; } c; c.f = f;
  return (unsigned short)((c.u + 0x7fffu + ((c.u >> 16) & 1u)) >> 16);
}
__device__ __forceinline__ float bf2f(uint32_t b) {
  union { uint32_t u; float f; } c; c.u = b << 16; return c.f;
}

// ---------- dtype detection ----------
// f32 adjacency words are only 0x00000000 / 0x3F800000. bf16-pair words
// (1.0,0.0)=0x00003F80 and (1.0,1.0)=0x3F803F80 cannot occur in f32 data.
// Scan first 16 MB (safe for both interpretations; buffer >= 134 MB).
__global__ __launch_bounds__(256) void k_detect(const uint32_t* __restrict__ a,
                                                int* __restrict__ flag) {
  int i = blockIdx.x * 256 + threadIdx.x;   // 65536 threads
  bool found = false;
  for (int k = 0; k < 64; k++) {
    uint32_t x = a[(size_t)k * 65536 + i];
    if (x == 0x00003F80u || x == 0x3F803F80u) found = true;
  }
  if (found) flag[0] = 1;   // benign same-value race
}

// ---------- CSR build ----------
// a_norm[b,i,j] nonzero iff adj[b,j,i] != 0; since adj is exactly 0/1,
// nnz count of CSR row i == colsum degree used by the reference.
__global__ __launch_bounds__(256) void k_build(const void* __restrict__ adjp,
                                               int* __restrict__ cnt,
                                               int* __restrict__ cols,
                                               const int* __restrict__ flag) {
  int gid = blockIdx.x * 256 + threadIdx.x;   // 32768 blocks -> 8388608 threads
  if (flag[0]) {
    // bf16: 67108864 ushorts as uint4 (8 elems each) -> 8388608 vectors
    const uint4* a = (const uint4*)adjp;
    uint4 v = a[gid];
    int i0 = (gid & 511) * 8;
    int j  = (gid >> 9) & 4095;
    int b  = gid >> 21;
    int base = b << 12;
    uint32_t w[4] = {v.x, v.y, v.z, v.w};
#pragma unroll
    for (int q = 0; q < 4; q++) {
      if (w[q] & 0xffffu) {
        int c = base + i0 + q * 2;
        int p = atomicAdd(&cnt[c], 1);
        if (p < CAP) cols[(size_t)c * CAP + p] = j;
      }
      if (w[q] >> 16) {
        int c = base + i0 + q * 2 + 1;
        int p = atomicAdd(&cnt[c], 1);
        if (p < CAP) cols[(size_t)c * CAP + p] = j;
      }
    }
  } else {
    // f32: 67108864 floats as float4 -> 16777216 vectors, 2 per thread
    const float4* a = (const float4*)adjp;
#pragma unroll
    for (int it = 0; it < 2; it++) {
      int v4 = gid + it * 8388608;
      float4 v = a[v4];
      int i0 = (v4 & 1023) * 4;
      int j  = (v4 >> 10) & 4095;
      int b  = v4 >> 22;
      int base = b << 12;
      float e[4] = {v.x, v.y, v.z, v.w};
#pragma unroll
      for (int q = 0; q < 4; q++) {
        if (e[q] != 0.0f) {
          int c = base + i0 + q;
          int p = atomicAdd(&cnt[c], 1);
          if (p < CAP) cols[(size_t)c * CAP + p] = j;
        }
      }
    }
  }
}

__global__ __launch_bounds__(256) void k_dinv(const int* __restrict__ cnt,
                                              float* __restrict__ dinv) {
  int i = blockIdx.x * 256 + threadIdx.x;   // 16384
  int c = cnt[i];
  dinv[i] = (c > 0) ? 1.0f / sqrtf((float)c) : 0.0f;
}

// ---------- conversions ----------
__global__ __launch_bounds__(256) void k_convx(const void* __restrict__ xp,
                                               ushort* __restrict__ xb,
                                               const int* __restrict__ flag) {
  int gid = blockIdx.x * 256 + threadIdx.x;  // 4096*256 = 1048576
  if (flag[0]) {
    const uint4* in = (const uint4*)xp;      // plain 16B copy, 1048576 vecs
    ((uint4*)xb)[gid] = in[gid];
  } else {
    const float4* in = (const float4*)xp;    // 2097152 float4s
#pragma unroll
    for (int it = 0; it < 2; it++) {
      int i = gid + it * 1048576;
      float4 v = in[i];
      uint32_t lo = (uint32_t)f2bf(v.x) | ((uint32_t)f2bf(v.y) << 16);
      uint32_t hi = (uint32_t)f2bf(v.z) | ((uint32_t)f2bf(v.w) << 16);
      ((uint2*)xb)[i] = make_uint2(lo, hi);
    }
  }
}

// WT[n][k] = bf16(W[k][n])  (512x512)
__global__ __launch_bounds__(256) void k_wconv(const void* __restrict__ wp,
                                               ushort* __restrict__ wt,
                                               const int* __restrict__ flag) {
  int o = blockIdx.x * 256 + threadIdx.x;    // 262144
  int n = o >> 9, k = o & 511;
  if (flag[0]) wt[o] = ((const ushort*)wp)[k * 512 + n];
  else         wt[o] = f2bf(((const float*)wp)[k * 512 + n]);
}

__global__ __launch_bounds__(256) void k_bconv(const void* __restrict__ bp,
                                               float* __restrict__ bf,
                                               const int* __restrict__ flag) {
  int i = blockIdx.x * 256 + threadIdx.x;    // 512
  bf[i] = flag[0] ? bf2f(((const ushort*)bp)[i]) : ((const float*)bp)[i];
}

// ---------- bf16 MFMA GEMM: Z[M,512] = X[M,512] @ W  (WT is [n][k]) ----------
__device__ __forceinline__ void gl_lds16(const ushort* g, ushort* l) {
  __builtin_amdgcn_global_load_lds((glb_u32*)g, (lds_u32*)l, 16, 0, 0);
}

__global__ __launch_bounds__(256) void k_gemm(const ushort* __restrict__ X,
                                              const ushort* __restrict__ WT,
                                              ushort* __restrict__ Z) {
  __shared__ ushort As[128 * 32];
  __shared__ ushort Bs[128 * 32];
  const int K = 512, NO = 512;
  int tid = threadIdx.x;
  int m0 = blockIdx.y * 128, n0 = blockIdx.x * 128;
  int lane = tid & 63;
  int wv = tid >> 6;
  int wm = (wv >> 1) << 6;   // wave tile origin within block tile
  int wn = (wv & 1) << 6;
  int lr = lane & 15;        // A/B row within 16, C col
  int lq = lane >> 4;        // quad

  f32x4 zero = {0.f, 0.f, 0.f, 0.f};
  f32x4 acc[4][4];
#pragma unroll
  for (int im = 0; im < 4; im++)
#pragma unroll
    for (int in_ = 0; in_ < 4; in_++) acc[im][in_] = zero;

  const ushort* Xg = X  + (size_t)(m0 + (tid >> 2)) * K + ((tid & 3) << 3);
  const ushort* Wg = WT + (size_t)(n0 + (tid >> 2)) * K + ((tid & 3) << 3);

  for (int kt = 0; kt < K; kt += 32) {
    __syncthreads();
    gl_lds16(Xg + kt,                    &As[tid * 8]);
    gl_lds16(Xg + kt + (size_t)64 * K,   &As[2048 + tid * 8]);
    gl_lds16(Wg + kt,                    &Bs[tid * 8]);
    gl_lds16(Wg + kt + (size_t)64 * K,   &Bs[2048 + tid * 8]);
    __syncthreads();
    bf16x8 af[4], bfr[4];
#pragma unroll
    for (int im = 0; im < 4; im++)
      af[im] = *(const bf16x8*)&As[(wm + im * 16 + lr) * 32 + lq * 8];
#pragma unroll
    for (int in_ = 0; in_ < 4; in_++)
      bfr[in_] = *(const bf16x8*)&Bs[(wn + in_ * 16 + lr) * 32 + lq * 8];
#pragma unroll
    for (int im = 0; im < 4; im++)
#pragma unroll
      for (int in_ = 0; in_ < 4; in_++)
        acc[im][in_] = __builtin_amdgcn_mfma_f32_16x16x32_bf16(
            af[im], bfr[in_], acc[im][in_], 0, 0, 0);
  }

#pragma unroll
  for (int im = 0; im < 4; im++) {
    int row0 = m0 + wm + im * 16 + lq * 4;
#pragma unroll
    for (int in_ = 0; in_ < 4; in_++) {
      int col = n0 + wn + in_ * 16 + lr;
#pragma unroll
      for (int r = 0; r < 4; r++)
        Z[(size_t)(row0 + r) * NO + col] = f2bf(acc[im][in_][r]);
    }
  }
}

// ---------- SpMM: out[r,:] = sum_j d_r*d_j * Z[j,:] (+bias, relu) ----------
__global__ __launch_bounds__(256) void k_spmm(const ushort* __restrict__ Z,
                                              const int* __restrict__ cnt,
                                              const int* __restrict__ cols,
                                              const float* __restrict__ dinv,
                                              const float* __restrict__ bias,
                                              void* __restrict__ outp,
                                              int do_relu, int is_final,
                                              const int* __restrict__ flag) {
  __shared__ int   sj[CAP];
  __shared__ float sv[CAP];
  int r = blockIdx.x;          // 16384 rows
  int b = r >> 12;
  int t = threadIdx.x;
  int nnz = cnt[r];
  if (nnz > CAP) nnz = CAP;
  if (t < nnz) {
    int j = cols[(size_t)r * CAP + t];
    sj[t] = j;
    sv[t] = dinv[r] * dinv[(b << 12) + j];
  }
  __syncthreads();

  const ushort* Zb = Z + ((size_t)(b << 12)) * 512 + (t << 1);
  float a0 = 0.f, a1 = 0.f;
  int k = 0;
  for (; k + 2 <= nnz; k += 2) {
    int j0 = sj[k], j1 = sj[k + 1];
    float v0 = sv[k], v1 = sv[k + 1];
    uint32_t z0 = *(const uint32_t*)(Zb + (size_t)j0 * 512);
    uint32_t z1 = *(const uint32_t*)(Zb + (size_t)j1 * 512);
    a0 += v0 * bf2f(z0 & 0xffffu);
    a1 += v0 * bf2f(z0 >> 16);
    a0 += v1 * bf2f(z1 & 0xffffu);
    a1 += v1 * bf2f(z1 >> 16);
  }
  if (k < nnz) {
    int j0 = sj[k]; float v0 = sv[k];
    uint32_t z0 = *(const uint32_t*)(Zb + (size_t)j0 * 512);
    a0 += v0 * bf2f(z0 & 0xffffu);
    a1 += v0 * bf2f(z0 >> 16);
  }
  float2 bb = *(const float2*)&bias[t << 1];
  a0 += bb.x; a1 += bb.y;
  if (do_relu) { a0 = fmaxf(a0, 0.f); a1 = fmaxf(a1, 0.f); }

  if (!is_final) {
    *(uint32_t*)((ushort*)outp + (size_t)r * 512 + (t << 1)) =
        (uint32_t)f2bf(a0) | ((uint32_t)f2bf(a1) << 16);
  } else if (flag[0]) {
    *(uint32_t*)((ushort*)outp + (size_t)r * 512 + (t << 1)) =
        (uint32_t)f2bf(a0) | ((uint32_t)f2bf(a1) << 16);
  } else {
    *(float2*)((float*)outp + (size_t)r * 512 + (t << 1)) = make_float2(a0, a1);
  }
}

extern "C" void kernel_launch(void* const* d_in, const int* in_sizes, int n_in,
                              void* d_out, int out_size, void* d_ws, size_t ws_size,
                              hipStream_t stream) {
  const void* X  = d_in[0];
  const void* A  = d_in[1];
  const void* W1 = d_in[2]; const void* b1 = d_in[3];
  const void* W2 = d_in[4]; const void* b2 = d_in[5];
  const void* W3 = d_in[6]; const void* b3 = d_in[7];

  char* ws = (char*)d_ws;
  size_t off = 0;
  auto alloc = [&](size_t bytes) -> void* {
    void* p = ws + off;
    off += (bytes + 255) & ~(size_t)255;
    return p;
  };
  int*    cnt  = (int*)alloc(16384 * 4);        // 64 KB
  int*    flag = (int*)alloc(4);                // 256 B slot, right after cnt
  float*  dinv = (float*)alloc(16384 * 4);
  int*    cols = (int*)alloc((size_t)16384 * CAP * 4);   // 8 MB
  ushort* W1T  = (ushort*)alloc(512 * 512 * 2);
  ushort* W2T  = (ushort*)alloc(512 * 512 * 2);
  ushort* W3T  = (ushort*)alloc(512 * 512 * 2);
  float*  b1f  = (float*)alloc(512 * 4);
  float*  b2f  = (float*)alloc(512 * 4);
  float*  b3f  = (float*)alloc(512 * 4);
  ushort* Xb   = (ushort*)alloc((size_t)16384 * 512 * 2);  // 16.8 MB
  ushort* Zb   = (ushort*)alloc((size_t)16384 * 512 * 2);
  ushort* Hb   = (ushort*)alloc((size_t)16384 * 512 * 2);

  hipMemsetAsync(cnt, 0, 65536 + 256, stream);   // cnt + flag

  k_detect<<<256, 256, 0, stream>>>((const uint32_t*)A, flag);
  k_build<<<32768, 256, 0, stream>>>(A, cnt, cols, flag);
  k_dinv<<<64, 256, 0, stream>>>(cnt, dinv);
  k_convx<<<4096, 256, 0, stream>>>(X, Xb, flag);
  k_wconv<<<1024, 256, 0, stream>>>(W1, W1T, flag);
  k_wconv<<<1024, 256, 0, stream>>>(W2, W2T, flag);
  k_wconv<<<1024, 256, 0, stream>>>(W3, W3T, flag);
  k_bconv<<<2, 256, 0, stream>>>(b1, b1f, flag);
  k_bconv<<<2, 256, 0, stream>>>(b2, b2f, flag);
  k_bconv<<<2, 256, 0, stream>>>(b3, b3f, flag);

  dim3 gg(4, 128);
  k_gemm<<<gg, 256, 0, stream>>>(Xb, W1T, Zb);
  k_spmm<<<16384, 256, 0, stream>>>(Zb, cnt, cols, dinv, b1f, Hb, 1, 0, flag);
  k_gemm<<<gg, 256, 0, stream>>>(Hb, W2T, Zb);
  k_spmm<<<16384, 256, 0, stream>>>(Zb, cnt, cols, dinv, b2f, Xb, 1, 0, flag);
  k_gemm<<<gg, 256, 0, stream>>>(Xb, W3T, Zb);
  k_spmm<<<16384, 256, 0, stream>>>(Zb, cnt, cols, dinv, b3f, d_out, 0, 1, flag);
}

// Round 2
// 601.065 us; speedup vs baseline: 1.2241x; 1.2241x over previous
//
#include <hip/hip_runtime.h>
#include <stdint.h>

#define CAP 128   // max nnz per normalized-adj row (Poisson(41): P(>=128) ~ 1e-26)
#define RPB 4     // rows per block in spmm (1 wave each)

typedef __attribute__((ext_vector_type(8))) short bf16x8;
typedef __attribute__((ext_vector_type(4))) float f32x4;

typedef __attribute__((address_space(3))) uint32_t lds_u32;
typedef __attribute__((address_space(1))) const uint32_t glb_u32;

__device__ __forceinline__ unsigned short f2bf(float f) {
  union { float f; uint32_t u; } c; c.f = f;
  return (unsigned short)((c.u + 0x7fffu + ((c.u >> 16) & 1u)) >> 16);
}
__device__ __forceinline__ float bf2f(uint32_t b) {
  union { uint32_t u; float f; } c; c.u = b << 16; return c.f;
}
__device__ __forceinline__ float as_f32(uint32_t u) {
  union { uint32_t u; float f; } c; c.u = u; return c.f;
}

// ---------- dtype detection ----------
// f32 adjacency words are only 0x00000000 / 0x3F800000. bf16-pair words
// (1.0,0.0)=0x00003F80 and (1.0,1.0)=0x3F803F80 cannot occur in f32 data.
__global__ __launch_bounds__(256) void k_detect(const uint32_t* __restrict__ a,
                                                int* __restrict__ flag) {
  int i = blockIdx.x * 256 + threadIdx.x;   // 65536 threads
  bool found = false;
  for (int k = 0; k < 64; k++) {
    uint32_t x = a[(size_t)k * 65536 + i];
    if (x == 0x00003F80u || x == 0x3F803F80u) found = true;
  }
  if (found) flag[0] = 1;   // benign same-value race
}

// ---------- CSR build ----------
__global__ __launch_bounds__(256) void k_build(const void* __restrict__ adjp,
                                               int* __restrict__ cnt,
                                               int* __restrict__ cols,
                                               const int* __restrict__ flag) {
  int gid = blockIdx.x * 256 + threadIdx.x;   // 32768 blocks -> 8388608 threads
  if (flag[0]) {
    const uint4* a = (const uint4*)adjp;
    uint4 v = a[gid];
    int i0 = (gid & 511) * 8;
    int j  = (gid >> 9) & 4095;
    int b  = gid >> 21;
    int base = b << 12;
    uint32_t w[4] = {v.x, v.y, v.z, v.w};
#pragma unroll
    for (int q = 0; q < 4; q++) {
      if (w[q] & 0xffffu) {
        int c = base + i0 + q * 2;
        int p = atomicAdd(&cnt[c], 1);
        if (p < CAP) cols[(size_t)c * CAP + p] = j;
      }
      if (w[q] >> 16) {
        int c = base + i0 + q * 2 + 1;
        int p = atomicAdd(&cnt[c], 1);
        if (p < CAP) cols[(size_t)c * CAP + p] = j;
      }
    }
  } else {
    const float4* a = (const float4*)adjp;
#pragma unroll
    for (int it = 0; it < 2; it++) {
      int v4 = gid + it * 8388608;
      float4 v = a[v4];
      int i0 = (v4 & 1023) * 4;
      int j  = (v4 >> 10) & 4095;
      int b  = v4 >> 22;
      int base = b << 12;
      float e[4] = {v.x, v.y, v.z, v.w};
#pragma unroll
      for (int q = 0; q < 4; q++) {
        if (e[q] != 0.0f) {
          int c = base + i0 + q;
          int p = atomicAdd(&cnt[c], 1);
          if (p < CAP) cols[(size_t)c * CAP + p] = j;
        }
      }
    }
  }
}

// ---------- dinv + bias conversion (merged) ----------
__global__ __launch_bounds__(256) void k_prep(const int* __restrict__ cnt,
                                              float* __restrict__ dinv,
                                              const void* b1, const void* b2,
                                              const void* b3,
                                              float* __restrict__ b1f,
                                              float* __restrict__ b2f,
                                              float* __restrict__ b3f,
                                              const int* __restrict__ flag) {
  int id = blockIdx.x * 256 + threadIdx.x;  // 70 blocks = 17920 threads
  if (id < 16384) {
    int c = cnt[id];
    dinv[id] = (c > 0) ? 1.0f / sqrtf((float)c) : 0.0f;
  } else {
    int o = id - 16384;
    if (o < 1536) {
      const void* src = (o < 512) ? b1 : (o < 1024) ? b2 : b3;
      float* dst = (o < 512) ? b1f : (o < 1024) ? b2f : b3f;
      int i = o & 511;
      dst[i] = flag[0] ? bf2f(((const ushort*)src)[i]) : ((const float*)src)[i];
    }
  }
}

// ---------- X conversion ----------
__global__ __launch_bounds__(256) void k_convx(const void* __restrict__ xp,
                                               ushort* __restrict__ xb,
                                               const int* __restrict__ flag) {
  int gid = blockIdx.x * 256 + threadIdx.x;  // 1048576
  if (flag[0]) {
    const uint4* in = (const uint4*)xp;
    ((uint4*)xb)[gid] = in[gid];
  } else {
    const float4* in = (const float4*)xp;
#pragma unroll
    for (int it = 0; it < 2; it++) {
      int i = gid + it * 1048576;
      float4 v = in[i];
      uint32_t lo = (uint32_t)f2bf(v.x) | ((uint32_t)f2bf(v.y) << 16);
      uint32_t hi = (uint32_t)f2bf(v.z) | ((uint32_t)f2bf(v.w) << 16);
      ((uint2*)xb)[i] = make_uint2(lo, hi);
    }
  }
}

// ---------- all 3 weights transposed+converted in one launch ----------
__global__ __launch_bounds__(256) void k_wconv(const void* w1, const void* w2,
                                               const void* w3,
                                               ushort* __restrict__ wt1,
                                               ushort* __restrict__ wt2,
                                               ushort* __restrict__ wt3,
                                               const int* __restrict__ flag) {
  int id = blockIdx.x * 256 + threadIdx.x;   // 3072 blocks
  int w = id >> 18;                          // 262144 elems each
  int o = id & 262143;
  const void* wp = (w == 0) ? w1 : (w == 1) ? w2 : w3;
  ushort* wt = (w == 0) ? wt1 : (w == 1) ? wt2 : wt3;
  int n = o >> 9, k = o & 511;
  if (flag[0]) wt[o] = ((const ushort*)wp)[k * 512 + n];
  else         wt[o] = f2bf(((const float*)wp)[k * 512 + n]);
}

// ---------- bf16 MFMA GEMM: Z[M,512] = X[M,512] @ W  (WT is [n][k]) ----------
__device__ __forceinline__ void gl_lds16(const ushort* g, ushort* l) {
  __builtin_amdgcn_global_load_lds((glb_u32*)g, (lds_u32*)l, 16, 0, 0);
}

__global__ __launch_bounds__(256) void k_gemm(const ushort* __restrict__ X,
                                              const ushort* __restrict__ WT,
                                              ushort* __restrict__ Z) {
  __shared__ ushort As[128 * 32];
  __shared__ ushort Bs[128 * 32];
  const int K = 512, NO = 512;
  int tid = threadIdx.x;
  int m0 = blockIdx.y * 128, n0 = blockIdx.x * 128;
  int lane = tid & 63;
  int wv = tid >> 6;
  int wm = (wv >> 1) << 6;
  int wn = (wv & 1) << 6;
  int lr = lane & 15;
  int lq = lane >> 4;

  f32x4 zero = {0.f, 0.f, 0.f, 0.f};
  f32x4 acc[4][4];
#pragma unroll
  for (int im = 0; im < 4; im++)
#pragma unroll
    for (int in_ = 0; in_ < 4; in_++) acc[im][in_] = zero;

  const ushort* Xg = X  + (size_t)(m0 + (tid >> 2)) * K + ((tid & 3) << 3);
  const ushort* Wg = WT + (size_t)(n0 + (tid >> 2)) * K + ((tid & 3) << 3);

  for (int kt = 0; kt < K; kt += 32) {
    __syncthreads();
    gl_lds16(Xg + kt,                    &As[tid * 8]);
    gl_lds16(Xg + kt + (size_t)64 * K,   &As[2048 + tid * 8]);
    gl_lds16(Wg + kt,                    &Bs[tid * 8]);
    gl_lds16(Wg + kt + (size_t)64 * K,   &Bs[2048 + tid * 8]);
    __syncthreads();
    bf16x8 af[4], bfr[4];
#pragma unroll
    for (int im = 0; im < 4; im++)
      af[im] = *(const bf16x8*)&As[(wm + im * 16 + lr) * 32 + lq * 8];
#pragma unroll
    for (int in_ = 0; in_ < 4; in_++)
      bfr[in_] = *(const bf16x8*)&Bs[(wn + in_ * 16 + lr) * 32 + lq * 8];
#pragma unroll
    for (int im = 0; im < 4; im++)
#pragma unroll
      for (int in_ = 0; in_ < 4; in_++)
        acc[im][in_] = __builtin_amdgcn_mfma_f32_16x16x32_bf16(
            af[im], bfr[in_], acc[im][in_], 0, 0, 0);
  }

#pragma unroll
  for (int im = 0; im < 4; im++) {
    int row0 = m0 + wm + im * 16 + lq * 4;
#pragma unroll
    for (int in_ = 0; in_ < 4; in_++) {
      int col = n0 + wn + in_ * 16 + lr;
#pragma unroll
      for (int r = 0; r < 4; r++)
        Z[(size_t)(row0 + r) * NO + col] = f2bf(acc[im][in_][r]);
    }
  }
}

// ---------- SpMM: out[r,:] = sum_j d_r*d_j * Z[j,:] (+bias, relu) ----------
// wave-per-row, dwordx4 gathers, XCD-batch affinity swizzle
__global__ __launch_bounds__(256) void k_spmm(const ushort* __restrict__ Z,
                                              const int* __restrict__ cnt,
                                              const int* __restrict__ cols,
                                              const float* __restrict__ dinv,
                                              const float* __restrict__ bias,
                                              void* __restrict__ outp,
                                              int do_relu, int is_final,
                                              const int* __restrict__ flag) {
  __shared__ int   sj[RPB][CAP];
  __shared__ float sv[RPB][CAP];
  int B = blockIdx.x;                 // 4096 blocks
  int wv = threadIdx.x >> 6;
  int lane = threadIdx.x & 63;
  // XCD affinity: XCD = B % 8 (round-robin dispatch); batch = (B&7)>>1 so
  // each XCD touches exactly one 4.2 MB batch slice of Z (fits its L2).
  int batch = (B & 7) >> 1;
  int lb = ((B >> 3) << 1) | (B & 1);           // [0,1024)
  int r = (batch << 12) + lb * RPB + wv;
  int base = batch << 12;

  int nnz = cnt[r];
  if (nnz > CAP) nnz = CAP;
  float dr = dinv[r];
  for (int k = lane; k < nnz; k += 64) {        // <=2 iterations (CAP=128)
    int j = cols[(size_t)r * CAP + k];
    sj[wv][k] = j;
    sv[wv][k] = dr * dinv[base + j];
  }
  // wave-local LDS producer/consumer: lgkmcnt ordering within the wave

  const ushort* Zb = Z + (size_t)base * 512 + lane * 8;
  const float4* bp = (const float4*)bias + lane * 2;
  float4 bb0 = bp[0], bb1 = bp[1];
  float a[8] = {bb0.x, bb0.y, bb0.z, bb0.w, bb1.x, bb1.y, bb1.z, bb1.w};

  int k = 0;
  for (; k + 2 <= nnz; k += 2) {
    int j0 = sj[wv][k], j1 = sj[wv][k + 1];
    float v0 = sv[wv][k], v1 = sv[wv][k + 1];
    uint4 z0 = *(const uint4*)(Zb + (size_t)j0 * 512);
    uint4 z1 = *(const uint4*)(Zb + (size_t)j1 * 512);
    uint32_t w0[4] = {z0.x, z0.y, z0.z, z0.w};
    uint32_t w1[4] = {z1.x, z1.y, z1.z, z1.w};
#pragma unroll
    for (int q = 0; q < 4; q++) {
      a[q * 2]     += v0 * as_f32(w0[q] << 16);
      a[q * 2 + 1] += v0 * as_f32(w0[q] & 0xffff0000u);
      a[q * 2]     += v1 * as_f32(w1[q] << 16);
      a[q * 2 + 1] += v1 * as_f32(w1[q] & 0xffff0000u);
    }
  }
  if (k < nnz) {
    int j0 = sj[wv][k];
    float v0 = sv[wv][k];
    uint4 z0 = *(const uint4*)(Zb + (size_t)j0 * 512);
    uint32_t w0[4] = {z0.x, z0.y, z0.z, z0.w};
#pragma unroll
    for (int q = 0; q < 4; q++) {
      a[q * 2]     += v0 * as_f32(w0[q] << 16);
      a[q * 2 + 1] += v0 * as_f32(w0[q] & 0xffff0000u);
    }
  }

  if (do_relu) {
#pragma unroll
    for (int q = 0; q < 8; q++) a[q] = fmaxf(a[q], 0.f);
  }

  if (!is_final || flag[0]) {
    uint4 o;
    o.x = (uint32_t)f2bf(a[0]) | ((uint32_t)f2bf(a[1]) << 16);
    o.y = (uint32_t)f2bf(a[2]) | ((uint32_t)f2bf(a[3]) << 16);
    o.z = (uint32_t)f2bf(a[4]) | ((uint32_t)f2bf(a[5]) << 16);
    o.w = (uint32_t)f2bf(a[6]) | ((uint32_t)f2bf(a[7]) << 16);
    *(uint4*)((ushort*)outp + (size_t)r * 512 + lane * 8) = o;
  } else {
    float4 o0 = make_float4(a[0], a[1], a[2], a[3]);
    float4 o1 = make_float4(a[4], a[5], a[6], a[7]);
    float4* op = (float4*)((float*)outp + (size_t)r * 512 + lane * 8);
    op[0] = o0; op[1] = o1;
  }
}

extern "C" void kernel_launch(void* const* d_in, const int* in_sizes, int n_in,
                              void* d_out, int out_size, void* d_ws, size_t ws_size,
                              hipStream_t stream) {
  const void* X  = d_in[0];
  const void* A  = d_in[1];
  const void* W1 = d_in[2]; const void* b1 = d_in[3];
  const void* W2 = d_in[4]; const void* b2 = d_in[5];
  const void* W3 = d_in[6]; const void* b3 = d_in[7];

  char* ws = (char*)d_ws;
  size_t off = 0;
  auto alloc = [&](size_t bytes) -> void* {
    void* p = ws + off;
    off += (bytes + 255) & ~(size_t)255;
    return p;
  };
  int*    cnt  = (int*)alloc(16384 * 4);
  int*    flag = (int*)alloc(4);
  float*  dinv = (float*)alloc(16384 * 4);
  int*    cols = (int*)alloc((size_t)16384 * CAP * 4);
  ushort* W1T  = (ushort*)alloc(512 * 512 * 2);
  ushort* W2T  = (ushort*)alloc(512 * 512 * 2);
  ushort* W3T  = (ushort*)alloc(512 * 512 * 2);
  float*  b1f  = (float*)alloc(512 * 4);
  float*  b2f  = (float*)alloc(512 * 4);
  float*  b3f  = (float*)alloc(512 * 4);
  ushort* Xb   = (ushort*)alloc((size_t)16384 * 512 * 2);
  ushort* Zb   = (ushort*)alloc((size_t)16384 * 512 * 2);
  ushort* Hb   = (ushort*)alloc((size_t)16384 * 512 * 2);

  hipMemsetAsync(cnt, 0, 65536 + 256, stream);   // cnt + flag

  k_detect<<<256, 256, 0, stream>>>((const uint32_t*)A, flag);
  k_build<<<32768, 256, 0, stream>>>(A, cnt, cols, flag);
  k_prep<<<70, 256, 0, stream>>>(cnt, dinv, b1, b2, b3, b1f, b2f, b3f, flag);
  k_convx<<<4096, 256, 0, stream>>>(X, Xb, flag);
  k_wconv<<<3072, 256, 0, stream>>>(W1, W2, W3, W1T, W2T, W3T, flag);

  dim3 gg(4, 128);
  k_gemm<<<gg, 256, 0, stream>>>(Xb, W1T, Zb);
  k_spmm<<<4096, 256, 0, stream>>>(Zb, cnt, cols, dinv, b1f, Hb, 1, 0, flag);
  k_gemm<<<gg, 256, 0, stream>>>(Hb, W2T, Zb);
  k_spmm<<<4096, 256, 0, stream>>>(Zb, cnt, cols, dinv, b2f, Xb, 1, 0, flag);
  k_gemm<<<gg, 256, 0, stream>>>(Xb, W3T, Zb);
  k_spmm<<<4096, 256, 0, stream>>>(Zb, cnt, cols, dinv, b3f, d_out, 0, 1, flag);
}